// Round 1
// baseline (1049.957 us; speedup 1.0000x reference)
//
#include <hip/hip_runtime.h>
#include <math.h>

#define L_SEQ 200
#define Q_DIM 128
#define H_DIM 128
#define QBATCH 8

// ---------------------------------------------------------------------------
// Kernel 1: qw[b,h] = sum_q query[b,q] * W[q,h]   (tiny: 0.27 GFLOP total)
// 256 threads, 8 batches per block. W read coalesced (L2-hot after 1st wave).
// ---------------------------------------------------------------------------
__global__ __launch_bounds__(256, 4) void qw_gemv(
    const float* __restrict__ query,   // [B, 128]
    const float* __restrict__ W,       // [128, 128]
    float* __restrict__ qw)            // [B, 128]
{
    const int t    = threadIdx.x;
    const int h    = t & 127;
    const int half = t >> 7;                 // 0 or 1: q-range [half*64, half*64+64)
    const int b0   = blockIdx.x * QBATCH;

    __shared__ float s_q[QBATCH][Q_DIM];         // 4 KB
    __shared__ float s_acc[2][QBATCH][H_DIM];    // 8 KB

    // load 8 query rows (256 float4 = 256 threads)
    {
        const int bb = t >> 5;
        const int f4 = t & 31;
        reinterpret_cast<float4*>(&s_q[bb][0])[f4] =
            reinterpret_cast<const float4*>(query + (size_t)(b0 + bb) * Q_DIM)[f4];
    }
    __syncthreads();

    float acc[QBATCH] = {};
    const float* Wcol = W + half * 64 * H_DIM + h;
    #pragma unroll 4
    for (int i = 0; i < 64; ++i) {
        const float wq = Wcol[i * H_DIM];        // coalesced across threads
        const int   q  = half * 64 + i;          // wave-uniform -> LDS broadcast
        #pragma unroll
        for (int bb = 0; bb < QBATCH; ++bb)
            acc[bb] = fmaf(s_q[bb][q], wq, acc[bb]);
    }
    #pragma unroll
    for (int bb = 0; bb < QBATCH; ++bb) s_acc[half][bb][h] = acc[bb];
    __syncthreads();

    #pragma unroll
    for (int k = 0; k < 4; ++k) {
        const int idx = k * 256 + t;
        const int bb  = idx >> 7;
        const int hh  = idx & 127;
        qw[(size_t)(b0 + bb) * H_DIM + hh] = s_acc[0][bb][hh] + s_acc[1][bb][hh];
    }
}

// ---------------------------------------------------------------------------
// Kernel 2: per-batch attention pooling. 512 threads = 8 waves per block.
// Thread t: lane32 = t&31 owns h-slice [lane32*4, lane32*4+4);
//           lgroup = t>>5 (0..15) owns rows {i*16 + lgroup}.
// r[13] = 52 VGPRs for the hist row -> total ~90 VGPRs, no spill,
// __launch_bounds__(512,4) -> 2 blocks/CU (16 waves). Only 2 barriers.
// hist loads issue at cycle 0 (no phase-0 dependency).
// ---------------------------------------------------------------------------
__global__ __launch_bounds__(512, 4) void attn_pool(
    const float* qw_all,               // [B, 128]  (may alias out)
    const float* __restrict__ hist,    // [B, 200, 128]
    const int*   __restrict__ lens,    // [B]
    float*       out)                  // [B, 128]
{
    const int b      = blockIdx.x;
    const int t      = threadIdx.x;
    const int lane32 = t & 31;
    const int lane64 = t & 63;
    const int lgroup = t >> 5;   // 0..15

    __shared__ float s_logits[L_SEQ];
    __shared__ float s_part[16 * H_DIM];   // 8 KB

    // ---------- issue hist loads immediately (coalesced: wave reads 1 KB) ----
    const float4* hbase =
        reinterpret_cast<const float4*>(hist + (size_t)b * (L_SEQ * H_DIM));
    float4 r[13];
    #pragma unroll
    for (int i = 0; i < 13; ++i) {
        const int l = i * 16 + lgroup;
        if (i < 12 || lgroup < 8)            // l < 200
            r[i] = hbase[l * 32 + lane32];
    }

    const float4 qw4 =
        reinterpret_cast<const float4*>(qw_all + (size_t)b * H_DIM)[lane32];
    const int len = lens[b];

    // ---------- pass 1: logits[l] = qw . hist[l,:]  (only needed for l>=len,
    // since l<len is masked to the constant 1e-9 before softmax) -------------
    #pragma unroll
    for (int i = 0; i < 13; ++i) {
        const int l = i * 16 + lgroup;
        if (i < 12 || lgroup < 8) {
            if (l >= len) {                  // uniform per 32-lane group
                float p = qw4.x * r[i].x + qw4.y * r[i].y
                        + qw4.z * r[i].z + qw4.w * r[i].w;
                p += __shfl_down(p, 16, 32);
                p += __shfl_down(p,  8, 32);
                p += __shfl_down(p,  4, 32);
                p += __shfl_down(p,  2, 32);
                p += __shfl_down(p,  1, 32);
                if (lane32 == 0) s_logits[l] = p;
            }
        }
    }
    __syncthreads();   // barrier 1: raw logits visible

    // ---------- softmax stats, computed redundantly per wave (no cross-wave
    // exchange, no extra barriers). Each wave scans all 200 entries. ---------
    float xs[4];
    float m = -3.0e38f;
    #pragma unroll
    for (int k = 0; k < 4; ++k) {
        const int l = lane64 + k * 64;
        float x = -3.0e38f;
        if (l < L_SEQ) {
            const float v = s_logits[l];     // garbage if l<len: discarded below
            x = (l < len) ? 1e-9f : v;
        }
        xs[k] = x;
        m = fmaxf(m, x);
    }
    m = fmaxf(m, __shfl_xor(m, 32, 64));
    m = fmaxf(m, __shfl_xor(m, 16, 64));
    m = fmaxf(m, __shfl_xor(m,  8, 64));
    m = fmaxf(m, __shfl_xor(m,  4, 64));
    m = fmaxf(m, __shfl_xor(m,  2, 64));
    m = fmaxf(m, __shfl_xor(m,  1, 64));

    float Z = 0.f;
    #pragma unroll
    for (int k = 0; k < 4; ++k)
        Z += __expf(xs[k] - m);              // l>=200 lanes: exp(-huge) = 0
    Z += __shfl_xor(Z, 32, 64);
    Z += __shfl_xor(Z, 16, 64);
    Z += __shfl_xor(Z,  8, 64);
    Z += __shfl_xor(Z,  4, 64);
    Z += __shfl_xor(Z,  2, 64);
    Z += __shfl_xor(Z,  1, 64);
    const float inv = 1.0f / Z;

    // ---------- pass 2: out[h] = sum_l score[l] * hist[l,h] -----------------
    float4 acc = make_float4(0.f, 0.f, 0.f, 0.f);
    #pragma unroll
    for (int i = 0; i < 13; ++i) {
        const int l = i * 16 + lgroup;
        if (i < 12 || lgroup < 8) {
            const float v = s_logits[l];     // LDS broadcast (uniform per group)
            const float x = (l < len) ? 1e-9f : v;
            const float s = __expf(x - m) * inv;
            acc.x = fmaf(s, r[i].x, acc.x);
            acc.y = fmaf(s, r[i].y, acc.y);
            acc.z = fmaf(s, r[i].z, acc.z);
            acc.w = fmaf(s, r[i].w, acc.w);
        }
    }
    reinterpret_cast<float4*>(s_part)[lgroup * 32 + lane32] = acc;
    __syncthreads();   // barrier 2

    if (t < H_DIM) {
        float v = 0.f;
        #pragma unroll
        for (int g = 0; g < 16; ++g) v += s_part[g * H_DIM + t];
        out[(size_t)b * H_DIM + t] = v;
    }
}

extern "C" void kernel_launch(void* const* d_in, const int* in_sizes, int n_in,
                              void* d_out, int out_size, void* d_ws, size_t ws_size,
                              hipStream_t stream) {
    const float* query = (const float*)d_in[0];   // [B, 128]
    const float* hist  = (const float*)d_in[1];   // [B, 200, 128]
    const int*   lens  = (const int*)d_in[2];     // [B]
    const float* W     = (const float*)d_in[3];   // [128, 128]
    float* out = (float*)d_out;                   // [B, 128]

    const int B = in_sizes[2];                    // 8192

    // qw scratch: workspace if large enough, else stage through `out`
    // (safe: each block of attn_pool reads qw[b] at entry and writes out[b]
    //  only at the very end, and block b is the only toucher of row b).
    float* qwbuf = (d_ws != nullptr && ws_size >= (size_t)B * H_DIM * sizeof(float))
                       ? (float*)d_ws : out;

    qw_gemv<<<dim3(B / QBATCH), dim3(256), 0, stream>>>(query, W, qwbuf);
    attn_pool<<<dim3(B), dim3(512), 0, stream>>>(qwbuf, hist, lens, out);
}